// Round 7
// baseline (850.601 us; speedup 1.0000x reference)
//
#include <hip/hip_runtime.h>

#define NPTS 6144
#define RESCALE (1.0f / 1024.0f)
#define NITER 10

// Triangle tiling: 48 tiles of 128 points, ib<=jb (1176 pairs).
// ONE persistent kernel (plain launch, graph-capture-safe): 512 blocks x 256
// thr -- co-resident by construction (max-VGPR capacity is exactly 2/CU x 256
// = 512; LDS 25.6KB allows 6/CU). Hand-rolled device-scope grid barrier
// between power iterations; per-iteration counters zeroed by prep each replay.
#define NB   48
#define BT   128
#define NTILE (NB * (NB + 1) / 2)   // 1176
#define GRID  512
#define MI   2                      // row-tiles per wave (32 rows)
#define JT   8                      // j-tiles (128/16)
#define ROWU 12                     // u32/row: mult of 4 -> 16B-aligned b128
#define OFF_A3 (BT * ROWU)
#define OFF_B2 (2 * BT * ROWU)
#define OFF_B3 (3 * BT * ROWU)
#define OFF_VJ (4 * BT * ROWU)
#define OFF_VI (OFF_VJ + BT)
#define OFF_Z  (OFF_VJ + 2 * BT)    // 16B zero pad for kb==3 reads
#define LDS_U32 (OFF_Z + 4)         // 6404 u32 = 25616 B

typedef unsigned short u16;
typedef unsigned int   u32;
typedef float v2f    __attribute__((ext_vector_type(2)));
typedef short bf16x8 __attribute__((ext_vector_type(8)));
typedef float f32x4  __attribute__((ext_vector_type(4)));

__device__ __forceinline__ u16 bsplit(float& x) {
  u32 u = __float_as_uint(x) & 0xFFFF0000u;
  x -= __uint_as_float(u);
  return (u16)(u >> 16);
}
__device__ __forceinline__ u32 pk(u16 lo, u16 hi) { return (u32)lo | ((u32)hi << 16); }

// Fragment packing (HW-verified rounds 2-4, absmax 6.1e-5):
//   a(i,j) = n2_i + n2_j - 2<p2_i,p2_j> via 3-way bf16 splits (K=18 of 32),
//   b(i,j) likewise for 3D (K=24 of 32). Slots 12..15 are implicit zeros.
__device__ __forceinline__ void build_i(float x2, float y2, float x3, float y3,
                                        float z3, u32* __restrict__ a2,
                                        u32* __restrict__ a3) {
  float n2 = fmaf(x2, x2, y2 * y2);
  float n3 = fmaf(x3, x3, fmaf(y3, y3, z3 * z3));
  const u16 ONE = 0x3F80;
  float t;
  t = -2.f * x2; u16 AXH = bsplit(t), AXM = bsplit(t), AXL = bsplit(t);
  t = -2.f * y2; u16 AYH = bsplit(t), AYM = bsplit(t), AYL = bsplit(t);
  t = n2;        u16 N2H = bsplit(t), N2M = bsplit(t), N2L = bsplit(t);
  t = -2.f * x3; u16 CXH = bsplit(t), CXM = bsplit(t), CXL = bsplit(t);
  t = -2.f * y3; u16 CYH = bsplit(t), CYM = bsplit(t), CYL = bsplit(t);
  t = -2.f * z3; u16 CZH = bsplit(t), CZM = bsplit(t), CZL = bsplit(t);
  t = n3;        u16 N3H = bsplit(t), N3M = bsplit(t), N3L = bsplit(t);
  a2[0] = pk(AXH, AYH); a2[1] = pk(AXM, AYM); a2[2] = pk(AXH, AYH); a2[3] = pk(AXM, AYM);
  a2[4] = pk(AXL, AYL); a2[5] = pk(AXH, AYH); a2[6] = pk(N2H, N2M); a2[7] = pk(N2L, ONE);
  a2[8] = pk(ONE, ONE); a2[9] = 0u; a2[10] = 0u; a2[11] = 0u;
  a3[0] = pk(CXH, CYH); a3[1]  = pk(CZH, CXM); a3[2]  = pk(CYM, CZM); a3[3]  = pk(CXH, CYH);
  a3[4] = pk(CZH, CXM); a3[5]  = pk(CYM, CZM); a3[6]  = pk(CXL, CYL); a3[7]  = pk(CZL, CXH);
  a3[8] = pk(CYH, CZH); a3[9]  = pk(N3H, N3M); a3[10] = pk(N3L, ONE); a3[11] = pk(ONE, ONE);
}

__device__ __forceinline__ void build_j(float x2, float y2, float x3, float y3,
                                        float z3, u32* __restrict__ b2,
                                        u32* __restrict__ b3) {
  float n2 = fmaf(x2, x2, y2 * y2);
  float n3 = fmaf(x3, x3, fmaf(y3, y3, z3 * z3));
  const u16 ONE = 0x3F80;
  float t;
  t = x2; u16 BXH = bsplit(t), BXM = bsplit(t), BXL = bsplit(t);
  t = y2; u16 BYH = bsplit(t), BYM = bsplit(t), BYL = bsplit(t);
  t = n2; u16 N2H = bsplit(t), N2M = bsplit(t), N2L = bsplit(t);
  t = x3; u16 DXH = bsplit(t), DXM = bsplit(t), DXL = bsplit(t);
  t = y3; u16 DYH = bsplit(t), DYM = bsplit(t), DYL = bsplit(t);
  t = z3; u16 DZH = bsplit(t), DZM = bsplit(t), DZL = bsplit(t);
  t = n3; u16 N3H = bsplit(t), N3M = bsplit(t), N3L = bsplit(t);
  b2[0] = pk(BXH, BYH); b2[1] = pk(BXH, BYH); b2[2] = pk(BXM, BYM); b2[3] = pk(BXM, BYM);
  b2[4] = pk(BXH, BYH); b2[5] = pk(BXL, BYL); b2[6] = pk(ONE, ONE); b2[7] = pk(ONE, N2H);
  b2[8] = pk(N2M, N2L); b2[9] = 0u; b2[10] = 0u; b2[11] = 0u;
  b3[0] = pk(DXH, DYH); b3[1]  = pk(DZH, DXH); b3[2]  = pk(DYH, DZH); b3[3]  = pk(DXM, DYM);
  b3[4] = pk(DZM, DXM); b3[5]  = pk(DYM, DZM); b3[6]  = pk(DXH, DYH); b3[7]  = pk(DZH, DXL);
  b3[8] = pk(DYL, DZL); b3[9]  = pk(ONE, ONE); b3[10] = pk(ONE, N3H); b3[11] = pk(N3M, N3L);
}

// Zero barrier counters, v0 = ones, zero iter-0 atomic target. Runs each
// graph replay -> whole pipeline idempotent.
__global__ __launch_bounds__(256) void prep_kernel(float* __restrict__ vA,
                                                   float* __restrict__ vB,
                                                   u32* __restrict__ cnt) {
  int i = blockIdx.x * 256 + threadIdx.x;
  if (i < NPTS) { vA[i] = 1.0f; vB[i] = 0.0f; }
  if (blockIdx.x == 0 && threadIdx.x < 16) cnt[threadIdx.x] = 0u;
}

// Device-scope grid barrier: all GRID blocks co-resident by construction.
__device__ __forceinline__ void gbar(u32* __restrict__ c) {
  __syncthreads();
  if (threadIdx.x == 0) {
    __hip_atomic_fetch_add(c, 1u, __ATOMIC_ACQ_REL, __HIP_MEMORY_SCOPE_AGENT);
    u32 v;
    do {
      __builtin_amdgcn_s_sleep(2);
      v = __hip_atomic_load(c, __ATOMIC_ACQUIRE, __HIP_MEMORY_SCOPE_AGENT);
    } while (v < (u32)GRID);
  }
  __syncthreads();
  __threadfence();   // acq_rel agent fence: invalidates L1 for fresh v reads
}

__global__ __launch_bounds__(256, 2) void sc2_kernel(
    const float* __restrict__ p2, const float* __restrict__ p3,
    float* __restrict__ b0, float* __restrict__ b1, float* __restrict__ b2v,
    u32* __restrict__ cnt, float* __restrict__ out) {
  __shared__ u32 sh[LDS_U32];
  float* shf = (float*)sh;

  const int bid  = blockIdx.x;
  const int t    = threadIdx.x;
  const int lane = t & 63;
  const int wv   = t >> 6;
  const int col  = lane & 15;
  const int kb   = lane >> 4;
  const int kb4  = kb * 4;
  const bool k3  = (kb == 3);

  if (t < 4) sh[OFF_Z + t] = 0u;   // LDS zero pad for kb==3 fragment reads

  const v2f kM100 = (v2f){-100.0f, -100.0f};
  const v2f k200  = (v2f){ 200.0f,  200.0f};
  const v2f kOne  = (v2f){   1.0f,    1.0f};
  const v2f kZero = (v2f){   0.0f,    0.0f};
  const f32x4 z4  = (f32x4){0.f, 0.f, 0.f, 0.f};

  float* va = b0;   // src (ones from prep)
  float* vb = b1;   // dst (zeroed by prep)
  float* vc = b2v;  // zeroed during this iter, dst next iter

  for (int it = 0; it < NITER; ++it) {
    const float* vsrc = va;
    float* vdst = vb;
    if (bid < NPTS / 256) vc[bid * 256 + t] = 0.0f;   // zero next dst

    for (int tl = bid; tl < NTILE; tl += GRID) {
      // Triangle decode: tl -> (ib <= jb)
      int r = (int)((sqrtf(8.f * (float)tl + 1.f) - 1.f) * 0.5f);
      while ((r + 1) * (r + 2) / 2 <= tl) ++r;
      while (r * (r + 1) / 2 > tl) --r;
      const int ib = tl - r * (r + 1) / 2;
      const int jb = r;
      const bool offd = (ib != jb);

      __syncthreads();   // previous tile's LDS readers done
      if (t < BT) {      // waves 0-1: i-side fragments + v_i
        const int ip = ib * BT + t;
        float x2 = p2[2 * ip], y2 = p2[2 * ip + 1];
        float x3 = p3[3 * ip], y3 = p3[3 * ip + 1], z3 = p3[3 * ip + 2];
        build_i(x2, y2, x3, y3, z3, &sh[t * ROWU], &sh[OFF_A3 + t * ROWU]);
        shf[OFF_VI + t] = vsrc[ip];
      } else {           // waves 2-3: j-side fragments + v_j
        const int tt = t - BT;
        const int jp = jb * BT + tt;
        float x2 = p2[2 * jp], y2 = p2[2 * jp + 1];
        float x3 = p3[3 * jp], y3 = p3[3 * jp + 1], z3 = p3[3 * jp + 2];
        build_j(x2, y2, x3, y3, z3, &sh[OFF_B2 + tt * ROWU],
                &sh[OFF_B3 + tt * ROWU]);
        shf[OFF_VJ + tt] = vsrc[jp];
      }
      __syncthreads();

      // A-fragments + v_i pairs to registers (kb==3 lanes read the zero pad).
      bf16x8 a2f[MI], a3f[MI];
      v2f vi2[MI][2];
#pragma unroll
      for (int mi = 0; mi < MI; ++mi) {
        const int rr = wv * 32 + mi * 16 + col;
        a2f[mi] = *(const bf16x8*)&sh[k3 ? OFF_Z : (rr * ROWU + kb4)];
        a3f[mi] = *(const bf16x8*)&sh[k3 ? OFF_Z : (OFF_A3 + rr * ROWU + kb4)];
#pragma unroll
        for (int p = 0; p < 2; ++p) {
          const int re = wv * 32 + mi * 16 + kb4 + 2 * p;
          vi2[mi][p] = (v2f){shf[OFF_VI + re], shf[OFF_VI + re + 1]};
        }
      }

      v2f racc[MI][2];
#pragma unroll
      for (int mi = 0; mi < MI; ++mi) {
        racc[mi][0] = (v2f){0.f, 0.f};
        racc[mi][1] = (v2f){0.f, 0.f};
      }

#pragma unroll
      for (int tj = 0; tj < JT; ++tj) {
        const int jrow = tj * 16 + col;
        const bf16x8 b2f = *(const bf16x8*)&sh[k3 ? OFF_Z : (OFF_B2 + jrow * ROWU + kb4)];
        const bf16x8 b3f = *(const bf16x8*)&sh[k3 ? OFF_Z : (OFF_B3 + jrow * ROWU + kb4)];
        const float vjs = shf[OFF_VJ + jrow];
        const v2f vj2 = (v2f){vjs, vjs};
        v2f cacc = (v2f){0.f, 0.f};
#pragma unroll
        for (int mi = 0; mi < MI; ++mi) {
          f32x4 aacc = __builtin_amdgcn_mfma_f32_16x16x32_bf16(a2f[mi], b2f, z4, 0, 0, 0);
          f32x4 bacc = __builtin_amdgcn_mfma_f32_16x16x32_bf16(a3f[mi], b3f, z4, 0, 0, 0);
#pragma unroll
          for (int p = 0; p < 2; ++p) {
            v2f a = (v2f){aacc[2 * p], aacc[2 * p + 1]};
            v2f b = (v2f){bacc[2 * p], bacc[2 * p + 1]};
            v2f ab = __builtin_elementwise_max(a * b, kZero);  // NaN guard near diag
            v2f s  = (v2f){__builtin_amdgcn_sqrtf(ab.x), __builtin_amdgcn_sqrtf(ab.y)};
            v2f w  = __builtin_elementwise_fma(a + b, kM100, kOne);
            w = __builtin_elementwise_fma(s, k200, w);
            w = __builtin_elementwise_max(w, kZero);
            racc[mi][p] = __builtin_elementwise_fma(w, vj2, racc[mi][p]);
            if (offd) cacc = __builtin_elementwise_fma(w, vi2[mi][p], cacc);
          }
        }
        if (offd) {  // column contribution: y[J] += S^T v_I (S symmetric)
          float c = cacc.x + cacc.y;
          c += __shfl_xor(c, 16);
          c += __shfl_xor(c, 32);
          if (lane < 16) atomicAdd(&vdst[jb * BT + tj * 16 + lane], c * RESCALE);
        }
      }

      // Row contribution: reduce across 16 columns, one atomic per row.
#pragma unroll
      for (int mi = 0; mi < MI; ++mi) {
#pragma unroll
        for (int p = 0; p < 2; ++p) {
          float r0 = racc[mi][p].x, r1 = racc[mi][p].y;
          r0 += __shfl_xor(r0, 1); r0 += __shfl_xor(r0, 2);
          r0 += __shfl_xor(r0, 4); r0 += __shfl_xor(r0, 8);
          r1 += __shfl_xor(r1, 1); r1 += __shfl_xor(r1, 2);
          r1 += __shfl_xor(r1, 4); r1 += __shfl_xor(r1, 8);
          if (col == 0) {
            const int row = ib * BT + wv * 32 + mi * 16 + kb4 + 2 * p;
            atomicAdd(&vdst[row],     r0 * RESCALE);
            atomicAdd(&vdst[row + 1], r1 * RESCALE);
          }
        }
      }
    }
    gbar(&cnt[it]);
    float* tmp = va; va = vb; vb = vc; vc = tmp;   // rotate buffers
  }

  // va holds the final (unnormalized) v. Blocks 0..23 normalize + write out.
  if (bid < NPTS / 256) {
    float ss = 0.0f;
    for (int k = t; k < NPTS; k += 256) {
      float x = va[k];
      ss = fmaf(x, x, ss);
    }
    for (int off = 32; off > 0; off >>= 1) ss += __shfl_down(ss, off, 64);
    __syncthreads();
    if ((t & 63) == 0) shf[t >> 6] = ss;
    __syncthreads();
    float tot = shf[0] + shf[1] + shf[2] + shf[3];
    float inv = 1.0f / (sqrtf(tot) + 1e-6f);
    const int i = bid * 256 + t;
    out[i] = va[i] * inv;
  }
}

extern "C" void kernel_launch(void* const* d_in, const int* in_sizes, int n_in,
                              void* d_out, int out_size, void* d_ws, size_t ws_size,
                              hipStream_t stream) {
  const float* p2 = (const float*)d_in[0];   // 6144 x 2, float32
  const float* p3 = (const float*)d_in[1];   // 6144 x 3, float32
  float* out = (float*)d_out;                // 6144, float32

  float* w = (float*)d_ws;
  float* b0 = w;
  float* b1 = w + 8192;
  float* b2v = w + 16384;
  u32*   cnt = (u32*)(w + 24576);   // 16 barrier counters

  prep_kernel<<<NPTS / 256, 256, 0, stream>>>(b0, b1, cnt);
  sc2_kernel<<<GRID, 256, 0, stream>>>(p2, p3, b0, b1, b2v, cnt, out);
}